// Round 1
// baseline (316.359 us; speedup 1.0000x reference)
//
#include <hip/hip_runtime.h>

// NGNNConv: out[i,j,:] = m[i,j] * [ (sum_{e: erow[e]=j} m[i,ecol[e]] * X[i,ecol[e],:]) @ W + b * cnt ]
// N=1024, E=8192, IND=OUTD=32, fp32.
//
// R3 design (block-per-i, polish of R2):
//  - X[i,:,:] streamed coalesced into LDS once, XOR-swizzled (p = seg ^ (k&7)),
//    PRE-MASKED (rows with mask[i,k]==0 are zeroed at staging time).
//  - cols[] staged into LDS as u16 with the per-i mask bit folded into bit 10,
//    so the edge loop is a pure branchless LDS stream:
//    ds_read_u16 + 8x ds_read_b128 + packed adds. cnt = sum of folded bits.
//  - Output staged back through LDS (same swizzle) for fully coalesced stores.

#define NN   1024
#define IND  32
#define OUTD 32
#define EE   8192

typedef __attribute__((ext_vector_type(2))) float f32x2;

// ---------------- CSR build (parallel, 4 tiny kernels) ----------------
__global__ __launch_bounds__(1024) void k_zero(int* __restrict__ p, int n) {
    const int t = blockIdx.x * 1024 + threadIdx.x;
    if (t < n) p[t] = 0;
}

__global__ __launch_bounds__(1024) void k_count(const int* __restrict__ erow,
                                                int* __restrict__ cnt, int n_edges) {
    const int e = blockIdx.x * 1024 + threadIdx.x;
    if (e < n_edges) atomicAdd(&cnt[erow[e]], 1);
}

__global__ __launch_bounds__(1024) void k_scan(const int* __restrict__ cnt,
                                               int* __restrict__ row_ptr,
                                               int* __restrict__ fill) {
    __shared__ int sb[NN];
    const int t = threadIdx.x;
    const int v = cnt[t];
    sb[t] = v;
    __syncthreads();
    #pragma unroll
    for (int off = 1; off < NN; off <<= 1) {
        const int a = (t >= off) ? sb[t - off] : 0;
        __syncthreads();
        sb[t] += a;
        __syncthreads();
    }
    const int excl = sb[t] - v;
    row_ptr[t] = excl;
    fill[t]    = excl;
    if (t == NN - 1) row_ptr[NN] = sb[t];
}

__global__ __launch_bounds__(1024) void k_scatter(const int* __restrict__ erow,
                                                  const int* __restrict__ ecol,
                                                  int* __restrict__ fill,
                                                  int* __restrict__ cols, int n_edges) {
    const int e = blockIdx.x * 1024 + threadIdx.x;
    if (e < n_edges) {
        const int pos = atomicAdd(&fill[erow[e]], 1);
        cols[pos] = ecol[e];
    }
}

// ---------------- main: block per i ----------------
__global__ __launch_bounds__(1024) void ngnn_main_kernel(
    const float* __restrict__ X, const int* __restrict__ mask,
    const float* __restrict__ W, const float* __restrict__ b,
    const int* __restrict__ row_ptr, const int* __restrict__ cols,
    float* __restrict__ out, int n_edges)
{
    extern __shared__ float smem[];
    float* Xl    = smem;                          // [1024][32] floats, seg-swizzled (128 KB)
    float* maskf = smem + NN * IND;               // [1024] floats (4 KB)
    unsigned short* colsl = (unsigned short*)(smem + NN * IND + NN); // [8192] u16 (16 KB)

    const int t = threadIdx.x;
    const int i = blockIdx.x;

    // ---- Phase 0: issue all global loads up front (latency overlap) ----
    const float4* Xg = (const float4*)(X + (size_t)i * NN * IND);
    float4 xv[8];
    #pragma unroll
    for (int it = 0; it < 8; ++it) xv[it] = Xg[it * 1024 + t];

    int cv[8];
    #pragma unroll
    for (int it = 0; it < 8; ++it) {
        const int e = it * 1024 + t;
        cv[it] = (e < n_edges) ? cols[e] : 0;
    }

    const int j  = t;
    const int e0 = row_ptr[j];
    const int e1 = row_ptr[j + 1];

    maskf[t] = (float)mask[(size_t)i * NN + t];
    __syncthreads();

    // ---- Phase 1: pre-masked X into swizzled LDS; cols+maskbit into LDS ----
    #pragma unroll
    for (int it = 0; it < 8; ++it) {
        const int f4 = it * 1024 + t;             // float4 index in the 128 KB slab
        const int k  = f4 >> 3;                   // row (8 float4 per row)
        const int p  = (f4 & 7) ^ (k & 7);        // swizzled segment slot
        const float m = maskf[k];                 // 8 lanes/addr -> LDS broadcast
        float4 v = xv[it];
        v.x *= m; v.y *= m; v.z *= m; v.w *= m;
        *(float4*)(Xl + (k << 5) + (p << 2)) = v;
    }
    #pragma unroll
    for (int it = 0; it < 8; ++it) {
        const int e = it * 1024 + t;
        if (e < n_edges && e < EE) {
            const int k = cv[it] & (NN - 1);
            colsl[e] = (unsigned short)(k | ((maskf[k] != 0.f) ? 1024 : 0));
        }
    }
    __syncthreads();

    // ---- Phase 2: branchless edge aggregation from LDS ----
    const float mj = maskf[j];
    f32x2 o2[16];

    if (mj != 0.f) {
        float4 S4[8];
        #pragma unroll
        for (int s = 0; s < 8; ++s) S4[s] = make_float4(0.f, 0.f, 0.f, 0.f);
        int cnt = 0;

        for (int e = e0; e < e1; ++e) {
            const int c = (int)colsl[e];          // ds_read_u16
            const int k = c & (NN - 1);
            cnt += c >> 10;                       // folded mask bit
            const float* rb = Xl + (k << 5);
            const int kb = (k & 7) << 2;
            #pragma unroll
            for (int s = 0; s < 8; ++s) {         // logical seg s lives at slot s^kb
                const float4 v = *(const float4*)(rb + ((s << 2) ^ kb));
                S4[s].x += v.x; S4[s].y += v.y; S4[s].z += v.z; S4[s].w += v.w;
            }
        }

        float S[IND];
        #pragma unroll
        for (int s = 0; s < 8; ++s) {
            S[4*s+0] = S4[s].x; S[4*s+1] = S4[s].y;
            S[4*s+2] = S4[s].z; S[4*s+3] = S4[s].w;
        }

        // ---- Phase 3: o = S@W + b*cnt. W/b wave-uniform -> s_load; f32x2 for pk-FMA.
        const float cntf = (float)cnt;
        const f32x2* W2 = (const f32x2*)W;
        const f32x2* b2 = (const f32x2*)b;
        #pragma unroll
        for (int c = 0; c < 16; ++c) o2[c] = b2[c] * cntf;
        #pragma unroll
        for (int d = 0; d < IND; ++d) {
            const float s = S[d];
            #pragma unroll
            for (int c = 0; c < 16; ++c) o2[c] += W2[d * 16 + c] * s;
        }
    } else {
        #pragma unroll
        for (int c = 0; c < 16; ++c) { o2[c].x = 0.f; o2[c].y = 0.f; }
    }

    // ---- Phase 4: stage output rows in LDS (swizzled), then coalesced store ----
    __syncthreads();                              // all phase-2 reads of Xl done
    #pragma unroll
    for (int q = 0; q < 8; ++q) {
        const int p = q ^ (j & 7);
        *(float4*)(Xl + (j << 5) + (p << 2)) =
            make_float4(o2[2*q].x, o2[2*q].y, o2[2*q+1].x, o2[2*q+1].y);
    }
    __syncthreads();
    float4* Og = (float4*)(out + (size_t)i * NN * IND);
    #pragma unroll
    for (int it = 0; it < 8; ++it) {
        const int f4 = it * 1024 + t;
        const int k  = f4 >> 3;
        const int p  = (f4 & 7) ^ (k & 7);
        Og[f4] = *(const float4*)(Xl + (k << 5) + (p << 2));
    }
}

extern "C" void kernel_launch(void* const* d_in, const int* in_sizes, int n_in,
                              void* d_out, int out_size, void* d_ws, size_t ws_size,
                              hipStream_t stream) {
    const float* X    = (const float*)d_in[0];
    const int*   mask = (const int*)d_in[1];
    const int*   erow = (const int*)d_in[2];
    const int*   ecol = (const int*)d_in[3];
    const float* W    = (const float*)d_in[4];
    const float* b    = (const float*)d_in[5];
    float*       out  = (float*)d_out;

    const int n_edges = in_sizes[2];

    // ws layout (ints): cnt[1024] | row_ptr[1025] @1024 | fill[1024] @2560 | cols @4096
    int* cnt     = (int*)d_ws;
    int* row_ptr = cnt + 1024;
    int* fill    = cnt + 2560;
    int* cols    = cnt + 4096;

    const int eb = (n_edges + 1023) / 1024;
    k_zero   <<<1, 1024, 0, stream>>>(cnt, NN);
    k_count  <<<eb, 1024, 0, stream>>>(erow, cnt, n_edges);
    k_scan   <<<1, 1024, 0, stream>>>(cnt, row_ptr, fill);
    k_scatter<<<eb, 1024, 0, stream>>>(erow, ecol, fill, cols, n_edges);

    const size_t shmem = (size_t)NN * IND * sizeof(float)   // Xl   128 KB
                       + (size_t)NN * sizeof(float)         // maskf  4 KB
                       + (size_t)EE * sizeof(unsigned short); // colsl 16 KB
    hipFuncSetAttribute((const void*)ngnn_main_kernel,
                        hipFuncAttributeMaxDynamicSharedMemorySize, (int)shmem);
    ngnn_main_kernel<<<NN, 1024, shmem, stream>>>(X, mask, W, b, row_ptr, cols, out, n_edges);
}